// Round 1
// baseline (3988.859 us; speedup 1.0000x reference)
//
#include <hip/hip_runtime.h>
#include <math.h>

// Problem constants
#define BB 8
#define CC 64        // Cin = Cout = AH
#define TT 16
#define HW 1024      // 32*32

// ws offsets (in floats)
#define OFF_Q   0u
#define OFF_K   524288u
#define OFF_V   1048576u
#define OFF_AX  1572864u
#define OFF_H0  2097152u
#define OFF_C   2621440u
#define OFF_H1  3145728u
#define OFF_WT  3670016u   // 294912 floats: [ic][ky][kx][oc]

// ---------------------------------------------------------------------------
// Transpose conv weights [oc][ic][ky][kx] -> [ (ic*3+ky)*3+kx ][oc]
__global__ __launch_bounds__(256) void k_wtrans(const float* __restrict__ conv_w,
                                                float* __restrict__ wT) {
    int idx = blockIdx.x * 256 + threadIdx.x;   // 294912 total
    if (idx >= 294912) return;
    int oc = idx & 255;
    int r  = idx >> 8;                          // ic*9 + ky*3 + kx
    wT[idx] = conv_w[oc * 1152 + r];
}

// ---------------------------------------------------------------------------
// QKV projection for timestep t.
// q/k/v stored as [b][o][n] (o = 0..63 per tensor), n = spatial index.
__global__ __launch_bounds__(256) void k_qkv(
    const float* __restrict__ X,
    const float* __restrict__ qw, const float* __restrict__ qb,
    const float* __restrict__ kw, const float* __restrict__ kb,
    const float* __restrict__ vw, const float* __restrict__ vb,
    float* __restrict__ qs, float* __restrict__ ks, float* __restrict__ vs,
    int t)
{
    __shared__ float xs[64][64];
    const int tid    = threadIdx.x;
    const int ntile  = blockIdx.x;   // 0..15 (64 n each)
    const int b      = blockIdx.y;   // 0..7
    const int osplit = blockIdx.z;   // 0..1 (96 outputs each)

    const float* xbase = X + ((size_t)(b * 64) * 16 + t) * 1024 + ntile * 64;
    for (int i = tid; i < 4096; i += 256) {
        int c = i >> 6, n = i & 63;
        xs[c][n] = xbase[(size_t)c * 16384 + n];
    }
    __syncthreads();

    const int og = __builtin_amdgcn_readfirstlane(tid >> 6);  // 0..3, wave-uniform
    const int n  = tid & 63;
    const int o0 = osplit * 96 + og * 24;

    float acc[24];
#pragma unroll
    for (int j = 0; j < 24; ++j) acc[j] = 0.f;

    for (int c0 = 0; c0 < 64; c0 += 16) {
        float xv[16];
#pragma unroll
        for (int cc = 0; cc < 16; ++cc) xv[cc] = xs[c0 + cc][n];
#pragma unroll
        for (int j = 0; j < 24; ++j) {
            int o = o0 + j;
            const float* wrow = (o < 64) ? (qw + o * 64)
                              : (o < 128) ? (kw + (o - 64) * 64)
                                          : (vw + (o - 128) * 64);
#pragma unroll
            for (int cc = 0; cc < 16; ++cc) acc[j] += wrow[c0 + cc] * xv[cc];
        }
    }

#pragma unroll
    for (int j = 0; j < 24; ++j) {
        int o = o0 + j;
        float* dst; float bias;
        if (o < 64)       { dst = qs + ((size_t)b * 64 + o)        * 1024; bias = qb[o]; }
        else if (o < 128) { dst = ks + ((size_t)b * 64 + (o - 64)) * 1024; bias = kb[o - 64]; }
        else              { dst = vs + ((size_t)b * 64 + (o - 128))* 1024; bias = vb[o - 128]; }
        dst[ntile * 64 + n] = acc[j] + bias;
    }
}

// ---------------------------------------------------------------------------
// Fused attention: ax[b][c][n] = softmax_m(q[n]·k[m]) @ v  (online softmax)
// block: (rowtile of 32 n, b). 256 threads: rg=tid>>5 (4 rows each), mlg=tid&31.
__global__ __launch_bounds__(256) void k_attn(
    const float* __restrict__ qs, const float* __restrict__ ks,
    const float* __restrict__ vs, float* __restrict__ ax)
{
    __shared__ float q_lds[32][66];
    __shared__ float k_lds[64][130];
    __shared__ float v_lds[128][68];   // [m][c]
    __shared__ float p_lds[32][130];

    const int tid = threadIdx.x;
    const int n0  = blockIdx.x * 32;
    const int b   = blockIdx.y;
    const float* qb_ = qs + (size_t)b * 65536;
    const float* kb_ = ks + (size_t)b * 65536;
    const float* vb_ = vs + (size_t)b * 65536;

    for (int i = tid; i < 2048; i += 256) {
        int o = i >> 5, r = i & 31;
        q_lds[r][o] = qb_[o * 1024 + n0 + r];
    }

    const int rg  = tid >> 5;   // 0..7  -> rows n0 + rg*4 + rr
    const int mlg = tid & 31;   // 0..31
    const int ch  = mlg & 7;    // c = 8*ch + cc
    const int mh  = mlg >> 3;   // 0..3  -> m = mh + 4*j in PV

    float m_run[4], l_run[4], acc[4][8];
#pragma unroll
    for (int rr = 0; rr < 4; ++rr) {
        m_run[rr] = -1e30f; l_run[rr] = 0.f;
#pragma unroll
        for (int cc = 0; cc < 8; ++cc) acc[rr][cc] = 0.f;
    }

    for (int mt = 0; mt < 8; ++mt) {
        // stage K,V tiles (128 m)
        for (int i = tid; i < 8192; i += 256) {
            int o = i >> 7, m = i & 127;
            k_lds[o][m] = kb_[o * 1024 + mt * 128 + m];
        }
        for (int i = tid; i < 8192; i += 256) {
            int c = i >> 7, m = i & 127;
            v_lds[m][c] = vb_[c * 1024 + mt * 128 + m];
        }
        __syncthreads();

        // phase 1: s[rr][j] for m = mlg + 32*j
        float s[4][4];
#pragma unroll
        for (int rr = 0; rr < 4; ++rr)
#pragma unroll
            for (int j = 0; j < 4; ++j) s[rr][j] = 0.f;
        for (int o = 0; o < 64; ++o) {
            float qv[4];
#pragma unroll
            for (int rr = 0; rr < 4; ++rr) qv[rr] = q_lds[rg * 4 + rr][o];
#pragma unroll
            for (int j = 0; j < 4; ++j) {
                float kv = k_lds[o][mlg + 32 * j];
#pragma unroll
                for (int rr = 0; rr < 4; ++rr) s[rr][j] += qv[rr] * kv;
            }
        }

        // online softmax update (reduce over the 32 mlg lanes of this row group)
        float p[4][4];
#pragma unroll
        for (int rr = 0; rr < 4; ++rr) {
            float tmax = s[rr][0];
#pragma unroll
            for (int j = 1; j < 4; ++j) tmax = fmaxf(tmax, s[rr][j]);
#pragma unroll
            for (int d = 1; d < 32; d <<= 1) tmax = fmaxf(tmax, __shfl_xor(tmax, d, 64));
            float nm = fmaxf(m_run[rr], tmax);
            float sc = expf(m_run[rr] - nm);
            float tsum = 0.f;
#pragma unroll
            for (int j = 0; j < 4; ++j) { p[rr][j] = expf(s[rr][j] - nm); tsum += p[rr][j]; }
#pragma unroll
            for (int d = 1; d < 32; d <<= 1) tsum += __shfl_xor(tsum, d, 64);
            l_run[rr] = l_run[rr] * sc + tsum;
            m_run[rr] = nm;
#pragma unroll
            for (int cc = 0; cc < 8; ++cc) acc[rr][cc] *= sc;
        }

        // publish p
#pragma unroll
        for (int rr = 0; rr < 4; ++rr)
#pragma unroll
            for (int j = 0; j < 4; ++j) p_lds[rg * 4 + rr][mlg + 32 * j] = p[rr][j];
        __syncthreads();

        // phase 2: PV. thread covers c = 8*ch..+7, m = mh + 4*j (quarter of tile)
#pragma unroll 4
        for (int j = 0; j < 32; ++j) {
            int m = mh + 4 * j;
            float pv[4];
#pragma unroll
            for (int rr = 0; rr < 4; ++rr) pv[rr] = p_lds[rg * 4 + rr][m];
            const float4* vp = reinterpret_cast<const float4*>(&v_lds[m][ch * 8]);
            float4 v0 = vp[0], v1 = vp[1];
            float vv[8] = {v0.x, v0.y, v0.z, v0.w, v1.x, v1.y, v1.z, v1.w};
#pragma unroll
            for (int rr = 0; rr < 4; ++rr)
#pragma unroll
                for (int cc = 0; cc < 8; ++cc) acc[rr][cc] += pv[rr] * vv[cc];
        }
        __syncthreads();   // p2 done before next tile restages k/v
    }

    // combine the 4 m-quarter partials (lanes differing in mh: tid bits 3,4)
#pragma unroll
    for (int rr = 0; rr < 4; ++rr)
#pragma unroll
        for (int cc = 0; cc < 8; ++cc) {
            float a = acc[rr][cc];
            a += __shfl_xor(a, 8, 64);
            a += __shfl_xor(a, 16, 64);
            acc[rr][cc] = a;
        }
    if (mh == 0) {
        float* axb = ax + (size_t)b * 65536;
#pragma unroll
        for (int rr = 0; rr < 4; ++rr) {
            float inv = 1.f / l_run[rr];
#pragma unroll
            for (int cc = 0; cc < 8; ++cc)
                axb[(ch * 8 + cc) * 1024 + n0 + rg * 4 + rr] = acc[rr][cc] * inv;
        }
    }
}

// ---------------------------------------------------------------------------
// Fused 3x3 conv (128->256) + ConvLSTM gates for timestep t.
// block: (tile 8w x 4h, b). z = concat(ax, h_prev).
__global__ __launch_bounds__(256) void k_conv(
    const float* __restrict__ ax, const float* __restrict__ hin,
    float* __restrict__ hout, float* __restrict__ cst,
    const float* __restrict__ wT, const float* __restrict__ conv_b,
    const float* __restrict__ wci, const float* __restrict__ wcf,
    const float* __restrict__ wco, float* __restrict__ out, int t)
{
    __shared__ float z_lds[128][60];     // [ic][row*10+col], rows 6, cols 10 (halo)
    __shared__ float conv_lds[32][260];  // [px][oc] (pad 260)

    const int tid  = threadIdx.x;
    const int tile = blockIdx.x;         // 0..31
    const int b    = blockIdx.y;
    const int x0   = (tile & 3) * 8;
    const int y0   = (tile >> 2) * 4;
    const float* axb = ax  + (size_t)b * 65536;
    const float* hb  = hin + (size_t)b * 65536;

    for (int i = tid; i < 7680; i += 256) {
        int ic  = i / 60;
        int rem = i - ic * 60;
        int row = rem / 10;
        int col = rem - row * 10;
        int gy = y0 + row - 1, gx = x0 + col - 1;
        float v = 0.f;
        if ((unsigned)gy < 32u && (unsigned)gx < 32u) {
            const float* src = (ic < 64) ? (axb + ic * 1024) : (hb + (ic - 64) * 1024);
            v = src[gy * 32 + gx];
        }
        z_lds[ic][rem] = v;
    }
    __syncthreads();

    const int ocg   = tid >> 3;          // 0..31 -> oc = ocg*8..+7
    const int pxg   = tid & 7;
    const int y_loc = pxg >> 1;          // 0..3
    const int x_loc = (pxg & 1) * 4;

    float acc[4][8];
#pragma unroll
    for (int pp = 0; pp < 4; ++pp)
#pragma unroll
        for (int o8 = 0; o8 < 8; ++o8) acc[pp][o8] = conv_b[ocg * 8 + o8];

    for (int ic = 0; ic < 128; ++ic) {
#pragma unroll
        for (int ky = 0; ky < 3; ++ky) {
            float in6[6];
#pragma unroll
            for (int q6 = 0; q6 < 6; ++q6)
                in6[q6] = z_lds[ic][(y_loc + ky) * 10 + x_loc + q6];
#pragma unroll
            for (int kx = 0; kx < 3; ++kx) {
                const float4* wp = reinterpret_cast<const float4*>(
                    wT + ((ic * 3 + ky) * 3 + kx) * 256 + ocg * 8);
                float4 w0 = wp[0], w1 = wp[1];
                float wv[8] = {w0.x, w0.y, w0.z, w0.w, w1.x, w1.y, w1.z, w1.w};
#pragma unroll
                for (int pp = 0; pp < 4; ++pp)
#pragma unroll
                    for (int o8 = 0; o8 < 8; ++o8)
                        acc[pp][o8] += wv[o8] * in6[kx + pp];
            }
        }
    }

    const int px_base = y_loc * 8 + x_loc;
#pragma unroll
    for (int pp = 0; pp < 4; ++pp) {
        float4* dst = reinterpret_cast<float4*>(&conv_lds[px_base + pp][ocg * 8]);
        dst[0] = make_float4(acc[pp][0], acc[pp][1], acc[pp][2], acc[pp][3]);
        dst[1] = make_float4(acc[pp][4], acc[pp][5], acc[pp][6], acc[pp][7]);
    }
    __syncthreads();

    // gates: thread = (chan = tid>>2, pxq = tid&3), 8 pixels each
    const int chan = tid >> 2;
    const int pxq  = tid & 3;
    float* cb  = cst  + (size_t)b * 65536 + chan * 1024;
    float* hob = hout + (size_t)b * 65536 + chan * 1024;
    float* ob  = out  + (((size_t)b * 64 + chan) * 16 + t) * 1024;
    const float* wcib = wci + chan * 1024;
    const float* wcfb = wcf + chan * 1024;
    const float* wcob = wco + chan * 1024;
#pragma unroll
    for (int q = 0; q < 8; ++q) {
        int px = pxq * 8 + q;
        int n  = (y0 + pxq) * 32 + x0 + q;
        float ic_ = conv_lds[px][chan];
        float fc_ = conv_lds[px][64 + chan];
        float gc_ = conv_lds[px][128 + chan];
        float oc_ = conv_lds[px][192 + chan];
        float cprev = cb[n];
        float iv = 1.f / (1.f + expf(-(ic_ + wcib[n] * cprev)));
        float fv = 1.f / (1.f + expf(-(fc_ + wcfb[n] * cprev)));
        float nc = fv * cprev + iv * tanhf(gc_);
        float ov = 1.f / (1.f + expf(-(oc_ + wcob[n] * nc)));
        float nh = ov * tanhf(nc);
        cb[n]  = nc;
        hob[n] = nh;
        ob[n]  = nh;
    }
}

// ---------------------------------------------------------------------------
extern "C" void kernel_launch(void* const* d_in, const int* in_sizes, int n_in,
                              void* d_out, int out_size, void* d_ws, size_t ws_size,
                              hipStream_t stream)
{
    const float* X   = (const float*)d_in[0];
    const float* qw  = (const float*)d_in[1];
    const float* qb  = (const float*)d_in[2];
    const float* kw  = (const float*)d_in[3];
    const float* kb  = (const float*)d_in[4];
    const float* vw  = (const float*)d_in[5];
    const float* vb  = (const float*)d_in[6];
    const float* cw  = (const float*)d_in[7];
    const float* cb  = (const float*)d_in[8];
    const float* wci = (const float*)d_in[9];
    const float* wcf = (const float*)d_in[10];
    const float* wco = (const float*)d_in[11];
    float* out = (float*)d_out;
    float* ws  = (float*)d_ws;

    float* qs_ = ws + OFF_Q;
    float* ks_ = ws + OFF_K;
    float* vs_ = ws + OFF_V;
    float* ax_ = ws + OFF_AX;
    float* h0_ = ws + OFF_H0;
    float* c_  = ws + OFF_C;
    float* h1_ = ws + OFF_H1;
    float* wT_ = ws + OFF_WT;

    // zero h0 and c (adjacent regions)
    hipMemsetAsync(h0_, 0, 2u * 524288u * sizeof(float), stream);
    k_wtrans<<<1152, 256, 0, stream>>>(cw, wT_);

    for (int t = 0; t < 16; ++t) {
        k_qkv<<<dim3(16, 8, 2), 256, 0, stream>>>(X, qw, qb, kw, kb, vw, vb,
                                                  qs_, ks_, vs_, t);
        k_attn<<<dim3(32, 8), 256, 0, stream>>>(qs_, ks_, vs_, ax_);
        float* hin  = (t & 1) ? h1_ : h0_;
        float* hout = (t & 1) ? h0_ : h1_;
        k_conv<<<dim3(32, 8), 256, 0, stream>>>(ax_, hin, hout, c_, wT_, cb,
                                                wci, wcf, wco, out, t);
    }
}